// Round 6
// baseline (150.891 us; speedup 1.0000x reference)
//
#include <hip/hip_runtime.h>

#define HH 128
#define WW 128
#define CC 64
#define CO 64
#define BB 4
#define GG 8
#define CG 8
#define KK 9
#define HW (HH*WW)
#define PXT 16
#define NCH 18             // k''-chunks of 32: 576/32, no padding
#define NPOS (GG*KK*PXT)   // 1152 positions per block

typedef __attribute__((ext_vector_type(8))) short short8;
typedef __attribute__((ext_vector_type(4))) float floatx4;

union S8I { short8 s; int i[4]; };

__device__ inline short f2bf(float f) {
    union { float f; unsigned u; } v; v.f = f;
    return (short)((v.u + 0x7FFF + ((v.u >> 16) & 1)) >> 16);
}
__device__ inline unsigned rnd_bf(float f) {   // rounded, bf16 in bits [31:16]
    union { float f; unsigned u; } v; v.f = f;
    return v.u + 0x7FFF + ((v.u >> 16) & 1);
}
__device__ inline float bflo(int e) { union { int i; float f; } u; u.i = e << 16; return u.f; }
__device__ inline float bfhi(int e) { union { int i; float f; } u; u.i = e & 0xffff0000; return u.f; }

// ---- merged prep: blocks [0,144) pack weights; blocks [144,2192) transpose input ----
// Weights -> A-fragments over continuous k'' = (g*9+kk)*8 + cg (K=576, 18 chunks):
//   wf[(gc*4+ot)*512 + L*8 + j] = bf16(W[o=ot*16+(L&15)][k''=gc*32+(L>>4)*8+j])
// Input NCHW f32 -> in_t[b][g][y*W+x][cg] bf16 (16B per pixel-group).
__global__ __launch_bounds__(256)
void prep(const float* __restrict__ wt, const float* __restrict__ in,
          short* __restrict__ wf, short* __restrict__ in_t) {
    const int bid = blockIdx.x;
    if (bid < 144) {
        const int tid = bid * 256 + threadIdx.x;      // < 36864 = 576*64
        const int j  = tid & 7;
        const int L  = (tid >> 3) & 63;
        const int fid = tid >> 9;                     // 0..71
        const int ot = fid & 3;
        const int gc = fid >> 2;                      // 0..17
        const int kpp = gc * 32 + (L >> 4) * 8 + j;   // k'' in [0,576)
        const int o   = ot * 16 + (L & 15);
        const int cg  = kpp & 7;
        const int t72 = kpp >> 3;                     // g*9+kk
        const int g   = t72 / 9, kk = t72 - g * 9;
        wf[tid] = f2bf(wt[o * 576 + (g * 8 + cg) * 9 + kk]);
    } else {
        const int idx = bid - 144;                    // 2048 blocks: 64 x 8 x 4
        const int bx = idx & 63;
        const int g  = (idx >> 6) & 7;
        const int b  = idx >> 9;
        const int p  = bx * 256 + threadIdx.x;
        const float* src = in + (b * CC + g * CG) * HW + p;
        short8 v;
        #pragma unroll
        for (int cg = 0; cg < CG; ++cg) v[cg] = f2bf(src[cg * HW]);
        *(short8*)(in_t + ((b * GG + g) * HW + p) * 8) = v;
    }
}

// Block: 256 thr / 4 waves, tile = (b, ho, 16 px) -> 64o x 16px. Grid (8,128,4)=4096.
// One barrier; s_col = 18 KB (no pad) -> 8 blocks/CU; 18 MFMA chunks.
__global__ __launch_bounds__(256, 8)
void dcn_fused(const short* __restrict__ in_t, const float* __restrict__ off,
               const float* __restrict__ msk, const short* __restrict__ wf,
               const float* __restrict__ bias, float* __restrict__ out)
{
    __shared__ short s_col[NCH * 512];   // [gc][lane][8] = 18432 B

    const int pxbase = blockIdx.x * PXT;
    const int ho = blockIdx.y;
    const int b  = blockIdx.z;
    const int t  = threadIdx.x;
    const int w = t >> 6, lane = t & 63;

    // ---- prefetch ALL offset/mask for this thread's positions (15 loads in flight) ----
    float pdy[5], pdx[5], pm[5];
    #pragma unroll
    for (int i = 0; i < 5; ++i) {
        const int pidx = t + i * 256;
        if (pidx < NPOS) {
            const int tc = pidx >> 4;            // g*9+kk, 0..71
            const int g  = tc / 9, kk = tc - g * 9;
            const int px = pxbase + (pidx & 15);
            const int base = ho * WW + px;
            const int offc = (b * 144 + g * 18 + kk * 2) * HW + base;
            pdy[i] = off[offc];
            pdx[i] = off[offc + HW];
            pm[i]  = msk[(b * 72 + g * 9 + kk) * HW + base];
        }
    }

    // ---- acc init from bias (C/D: row o = w*16 + q4*4 + r, col px = n16) ----
    const int q4 = lane >> 4, n16 = lane & 15;
    floatx4 acc0, acc1;
    #pragma unroll
    for (int r = 0; r < 4; ++r) { acc0[r] = bias[w * 16 + q4 * 4 + r]; acc1[r] = 0.f; }

    // ---- gather phase: no barriers, max MLP ----
    const short* inb = in_t + (long)b * GG * HW * 8;
    #pragma unroll
    for (int i = 0; i < 5; ++i) {
        const int pidx = t + i * 256;
        if (pidx < NPOS) {
            const int tc = pidx >> 4;
            const int g  = tc / 9, kk = tc - g * 9;
            const int pl = pidx & 15;
            const int px = pxbase + pl;
            const int ky = kk / 3, kx = kk - ky * 3;

            const float py  = (float)(ho - 1 + ky) + pdy[i];
            const float pxf = (float)(px - 1 + kx) + pdx[i];
            const float y0f = floorf(py), x0f = floorf(pxf);
            const float ly = py - y0f, lx = pxf - x0f;
            const int y0 = (int)y0f, x0 = (int)x0f;
            const int y1 = y0 + 1,  x1 = x0 + 1;

            const float vy0 = (y0 >= 0 && y0 < HH) ? 1.f : 0.f;
            const float vy1 = (y1 >= 0 && y1 < HH) ? 1.f : 0.f;
            const float vx0 = (x0 >= 0 && x0 < WW) ? 1.f : 0.f;
            const float vx1 = (x1 >= 0 && x1 < WW) ? 1.f : 0.f;
            const int y0c = min(max(y0, 0), HH - 1), y1c = min(max(y1, 0), HH - 1);
            const int x0c = min(max(x0, 0), WW - 1), x1c = min(max(x1, 0), WW - 1);

            const float m = pm[i];
            const float w00 = (1.f - ly) * (1.f - lx) * vy0 * vx0 * m;
            const float w01 = (1.f - ly) * lx         * vy0 * vx1 * m;
            const float w10 = ly         * (1.f - lx) * vy1 * vx0 * m;
            const float w11 = ly         * lx         * vy1 * vx1 * m;

            const short* ing = inb + g * (HW * 8);
            S8I u00, u01, u10, u11;
            u00.s = *(const short8*)(ing + (y0c * WW + x0c) * 8);
            u01.s = *(const short8*)(ing + (y0c * WW + x1c) * 8);
            u10.s = *(const short8*)(ing + (y1c * WW + x0c) * 8);
            u11.s = *(const short8*)(ing + (y1c * WW + x1c) * 8);

            S8I res;
            #pragma unroll
            for (int pc = 0; pc < 4; ++pc) {
                const int e00 = u00.i[pc], e01 = u01.i[pc];
                const int e10 = u10.i[pc], e11 = u11.i[pc];
                const float vx_ = w00 * bflo(e00) + w01 * bflo(e01)
                                + w10 * bflo(e10) + w11 * bflo(e11);
                const float vy_ = w00 * bfhi(e00) + w01 * bfhi(e01)
                                + w10 * bfhi(e10) + w11 * bfhi(e11);
                res.i[pc] = (int)__builtin_amdgcn_perm(rnd_bf(vy_), rnd_bf(vx_), 0x07060302u);
            }

            // k'' row = tc*8+cg -> fragment row index IS pidx: one 16B write
            *(short8*)(s_col + pidx * 8) = res.s;
        }
    }

    __syncthreads();   // the only barrier

    // ---- MFMA: 18 chunks, A-frags from L2-hot global, 2 acc chains ----
    #pragma unroll
    for (int gc = 0; gc < NCH; ++gc) {
        const short8 bfr = *(const short8*)&s_col[(gc * 64 + lane) * 8];
        const short8 afr = *(const short8*)&wf[((gc * 4 + w) * 64 + lane) * 8];
        if (gc & 1) acc1 = __builtin_amdgcn_mfma_f32_16x16x32_bf16(afr, bfr, acc1, 0, 0, 0);
        else        acc0 = __builtin_amdgcn_mfma_f32_16x16x32_bf16(afr, bfr, acc0, 0, 0, 0);
    }

    // ---- epilogue ----
    const int px = pxbase + n16;
    #pragma unroll
    for (int r = 0; r < 4; ++r) {
        const int o = w * 16 + q4 * 4 + r;
        out[((b * CO + o) * HH + ho) * WW + px] = acc0[r] + acc1[r];
    }
}

extern "C" void kernel_launch(void* const* d_in, const int* in_sizes, int n_in,
                              void* d_out, int out_size, void* d_ws, size_t ws_size,
                              hipStream_t stream) {
    const float* in   = (const float*)d_in[0];
    const float* off  = (const float*)d_in[1];
    const float* msk  = (const float*)d_in[2];
    const float* wt   = (const float*)d_in[3];
    const float* bias = (const float*)d_in[4];
    float* out = (float*)d_out;
    short* wf   = (short*)d_ws;            // 36864 shorts = 72 KB
    short* in_t = (short*)d_ws + 36864;    // 4*8*16384*8 shorts = 8 MB

    prep<<<144 + 2048, 256, 0, stream>>>(wt, in, wf, in_t);

    dim3 grid(WW / PXT, HH, BB);
    dcn_fused<<<grid, 256, 0, stream>>>(in_t, off, msk, wf, bias, out);
}

// Round 7
// 141.830 us; speedup vs baseline: 1.0639x; 1.0639x over previous
//
#include <hip/hip_runtime.h>

#define HH 128
#define WW 128
#define CC 64
#define CO 64
#define BB 4
#define GG 8
#define CG 8
#define KK 9
#define HW (HH*WW)
#define PXT 16
#define NCH 18             // k''-chunks of 32: 576/32, no padding
#define NPOS (GG*KK*PXT)   // 1152 positions per block

typedef __attribute__((ext_vector_type(8))) short short8;
typedef __attribute__((ext_vector_type(4))) float floatx4;

union S8I { short8 s; int i[4]; };

__device__ inline short f2bf(float f) {
    union { float f; unsigned u; } v; v.f = f;
    return (short)((v.u + 0x7FFF + ((v.u >> 16) & 1)) >> 16);
}
__device__ inline unsigned rnd_bf(float f) {   // rounded, bf16 in bits [31:16]
    union { float f; unsigned u; } v; v.f = f;
    return v.u + 0x7FFF + ((v.u >> 16) & 1);
}
__device__ inline float bflo(int e) { union { int i; float f; } u; u.i = e << 16; return u.f; }
__device__ inline float bfhi(int e) { union { int i; float f; } u; u.i = e & 0xffff0000; return u.f; }

// ---- merged prep: blocks [0,144) pack weights; blocks [144,2192) transpose input ----
__global__ __launch_bounds__(256)
void prep(const float* __restrict__ wt, const float* __restrict__ in,
          short* __restrict__ wf, short* __restrict__ in_t) {
    const int bid = blockIdx.x;
    if (bid < 144) {
        const int tid = bid * 256 + threadIdx.x;      // < 36864 = 576*64
        const int j  = tid & 7;
        const int L  = (tid >> 3) & 63;
        const int fid = tid >> 9;                     // 0..71
        const int ot = fid & 3;
        const int gc = fid >> 2;                      // 0..17
        const int kpp = gc * 32 + (L >> 4) * 8 + j;   // k'' in [0,576)
        const int o   = ot * 16 + (L & 15);
        const int cg  = kpp & 7;
        const int t72 = kpp >> 3;                     // g*9+kk
        const int g   = t72 / 9, kk = t72 - g * 9;
        wf[tid] = f2bf(wt[o * 576 + (g * 8 + cg) * 9 + kk]);
    } else {
        const int idx = bid - 144;                    // 2048 blocks: 64 x 8 x 4
        const int bx = idx & 63;
        const int g  = (idx >> 6) & 7;
        const int b  = idx >> 9;
        const int p  = bx * 256 + threadIdx.x;
        const float* src = in + (b * CC + g * CG) * HW + p;
        short8 v;
        #pragma unroll
        for (int cg = 0; cg < CG; ++cg) v[cg] = f2bf(src[cg * HW]);
        *(short8*)(in_t + ((b * GG + g) * HW + p) * 8) = v;
    }
}

// Block: 256 thr / 4 waves, tile = (b, ho, 16 px) -> 64o x 16px. Grid (8,128,4)=4096.
// One barrier. Gather is two-phase: ALL 20 corner loads issued before any
// bilinear math -> max memory-level parallelism (this kernel is gather-latency
// bound; round-6 showed TLP can't substitute for MLP here).
__global__ __launch_bounds__(256)
void dcn_fused(const short* __restrict__ in_t, const float* __restrict__ off,
               const float* __restrict__ msk, const short* __restrict__ wf,
               const float* __restrict__ bias, float* __restrict__ out)
{
    __shared__ short s_col[NCH * 512];   // [gc][lane][8] = 18432 B

    const int pxbase = blockIdx.x * PXT;
    const int ho = blockIdx.y;
    const int b  = blockIdx.z;
    const int t  = threadIdx.x;
    const int w = t >> 6, lane = t & 63;

    // ---- prefetch ALL offset/mask for this thread's positions (15 loads in flight) ----
    float pdy[5], pdx[5], pm[5];
    #pragma unroll
    for (int i = 0; i < 5; ++i) {
        const int pidx = t + i * 256;
        if (pidx < NPOS) {
            const int tc = pidx >> 4;            // g*9+kk, 0..71
            const int g  = tc / 9, kk = tc - g * 9;
            const int px = pxbase + (pidx & 15);
            const int base = ho * WW + px;
            const int offc = (b * 144 + g * 18 + kk * 2) * HW + base;
            pdy[i] = off[offc];
            pdx[i] = off[offc + HW];
            pm[i]  = msk[(b * 72 + g * 9 + kk) * HW + base];
        }
    }

    // ---- acc init from bias (C/D: row o = w*16 + q4*4 + r, col px = n16) ----
    const int q4 = lane >> 4, n16 = lane & 15;
    floatx4 acc0, acc1;
    #pragma unroll
    for (int r = 0; r < 4; ++r) { acc0[r] = bias[w * 16 + q4 * 4 + r]; acc1[r] = 0.f; }

    const short* inb = in_t + (long)b * GG * HW * 8;

    // ---- phase A: addresses + weights, issue all 20 corner loads ----
    S8I u00[5], u01[5], u10[5], u11[5];
    float w00[5], w01[5], w10[5], w11[5];
    #pragma unroll
    for (int i = 0; i < 5; ++i) {
        const int pidx = t + i * 256;
        if (pidx < NPOS) {
            const int tc = pidx >> 4;
            const int g  = tc / 9, kk = tc - g * 9;
            const int px = pxbase + (pidx & 15);
            const int ky = kk / 3, kx = kk - ky * 3;

            const float py  = (float)(ho - 1 + ky) + pdy[i];
            const float pxf = (float)(px - 1 + kx) + pdx[i];
            const float y0f = floorf(py), x0f = floorf(pxf);
            const float ly = py - y0f, lx = pxf - x0f;
            const int y0 = (int)y0f, x0 = (int)x0f;
            const int y1 = y0 + 1,  x1 = x0 + 1;

            const float vy0 = (y0 >= 0 && y0 < HH) ? 1.f : 0.f;
            const float vy1 = (y1 >= 0 && y1 < HH) ? 1.f : 0.f;
            const float vx0 = (x0 >= 0 && x0 < WW) ? 1.f : 0.f;
            const float vx1 = (x1 >= 0 && x1 < WW) ? 1.f : 0.f;
            const int y0c = min(max(y0, 0), HH - 1), y1c = min(max(y1, 0), HH - 1);
            const int x0c = min(max(x0, 0), WW - 1), x1c = min(max(x1, 0), WW - 1);

            const float m = pm[i];
            w00[i] = (1.f - ly) * (1.f - lx) * vy0 * vx0 * m;
            w01[i] = (1.f - ly) * lx         * vy0 * vx1 * m;
            w10[i] = ly         * (1.f - lx) * vy1 * vx0 * m;
            w11[i] = ly         * lx         * vy1 * vx1 * m;

            const short* ing = inb + g * (HW * 8);
            u00[i].s = *(const short8*)(ing + (y0c * WW + x0c) * 8);
            u01[i].s = *(const short8*)(ing + (y0c * WW + x1c) * 8);
            u10[i].s = *(const short8*)(ing + (y1c * WW + x0c) * 8);
            u11[i].s = *(const short8*)(ing + (y1c * WW + x1c) * 8);
        }
    }

    // ---- phase B: bilinear combine + bf16 pack + fragment write ----
    #pragma unroll
    for (int i = 0; i < 5; ++i) {
        const int pidx = t + i * 256;
        if (pidx < NPOS) {
            S8I res;
            #pragma unroll
            for (int pc = 0; pc < 4; ++pc) {
                const int e00 = u00[i].i[pc], e01 = u01[i].i[pc];
                const int e10 = u10[i].i[pc], e11 = u11[i].i[pc];
                const float vx_ = w00[i] * bflo(e00) + w01[i] * bflo(e01)
                                + w10[i] * bflo(e10) + w11[i] * bflo(e11);
                const float vy_ = w00[i] * bfhi(e00) + w01[i] * bfhi(e01)
                                + w10[i] * bfhi(e10) + w11[i] * bfhi(e11);
                res.i[pc] = (int)__builtin_amdgcn_perm(rnd_bf(vy_), rnd_bf(vx_), 0x07060302u);
            }
            // k'' row index IS pidx: one 16B write
            *(short8*)(s_col + pidx * 8) = res.s;
        }
    }

    __syncthreads();   // the only barrier

    // ---- MFMA: 18 chunks, A-frags from L2-hot global, 2 acc chains ----
    #pragma unroll
    for (int gc = 0; gc < NCH; ++gc) {
        const short8 bfr = *(const short8*)&s_col[(gc * 64 + lane) * 8];
        const short8 afr = *(const short8*)&wf[((gc * 4 + w) * 64 + lane) * 8];
        if (gc & 1) acc1 = __builtin_amdgcn_mfma_f32_16x16x32_bf16(afr, bfr, acc1, 0, 0, 0);
        else        acc0 = __builtin_amdgcn_mfma_f32_16x16x32_bf16(afr, bfr, acc0, 0, 0, 0);
    }

    // ---- epilogue ----
    const int px = pxbase + n16;
    #pragma unroll
    for (int r = 0; r < 4; ++r) {
        const int o = w * 16 + q4 * 4 + r;
        out[((b * CO + o) * HH + ho) * WW + px] = acc0[r] + acc1[r];
    }
}

extern "C" void kernel_launch(void* const* d_in, const int* in_sizes, int n_in,
                              void* d_out, int out_size, void* d_ws, size_t ws_size,
                              hipStream_t stream) {
    const float* in   = (const float*)d_in[0];
    const float* off  = (const float*)d_in[1];
    const float* msk  = (const float*)d_in[2];
    const float* wt   = (const float*)d_in[3];
    const float* bias = (const float*)d_in[4];
    float* out = (float*)d_out;
    short* wf   = (short*)d_ws;            // 36864 shorts = 72 KB
    short* in_t = (short*)d_ws + 36864;    // 4*8*16384*8 shorts = 8 MB

    prep<<<144 + 2048, 256, 0, stream>>>(wt, in, wf, in_t);

    dim3 grid(WW / PXT, HH, BB);
    dcn_fused<<<grid, 256, 0, stream>>>(in_t, off, msk, wf, bias, out);
}